// Round 3
// 322.684 us; speedup vs baseline: 1.0138x; 1.0138x over previous
//
#include <hip/hip_runtime.h>

// out[b,i,n] = sum_j w[i,j] * x[b,j,n]
// x: [B=256, 3, N=65536] fp32, w: [3,3] fp32, out: [B, 3, N] fp32.
// Pure streaming map: 402 MB HBM traffic, FLOPs negligible -> HBM-bound.
//
// Persistent grid-stride structure:
//   2048 blocks x 256 threads = 2^19 threads; total float4 groups = 2^22,
//   so each thread does exactly 8 triples. Since NTHREADS (2^19) is a
//   multiple of GPB (2^14), the grid-stride step keeps g fixed and advances
//   b by 32 -> base advances by the compile-time constant 32*3*GPB.
//   Full unroll gives the scheduler 24 independent loads to pipeline.
//   All element offsets < 2^24 -> 32-bit address math.
//   nt load/store: strictly-streamed data, no reuse to protect in cache.
//
// NOTE: __builtin_nontemporal_* rejects HIP_vector_type (a class); use a
// clang-native ext_vector_type instead (same 16B size/alignment).

typedef float f32x4 __attribute__((ext_vector_type(4)));

#define B_DIM    256
#define N_DIM    65536
#define GPB      (N_DIM / 4)          // float4 groups per (b, j) row = 16384
#define BLOCK    256
#define GRID     2048                 // 8 wg/CU * 256 CU
#define ITERS    8                    // (B_DIM*GPB) / (GRID*BLOCK), exact
#define IT_STEP  (32u * 3u * GPB)     // base advance per iteration (b += 32)

__global__ __launch_bounds__(BLOCK) void rot_kernel(
    const f32x4* __restrict__ x,
    const float* __restrict__ w,
    f32x4*       __restrict__ out)
{
    // 3x3 weight: wave-uniform addresses -> scalar loads, fully cached
    const float w00 = w[0], w01 = w[1], w02 = w[2];
    const float w10 = w[3], w11 = w[4], w12 = w[5];
    const float w20 = w[6], w21 = w[7], w22 = w[8];

    const unsigned idx0 = blockIdx.x * BLOCK + threadIdx.x;  // < 2^19
    const unsigned b0   = idx0 >> 14;                        // 0..31
    const unsigned g    = idx0 & (GPB - 1u);

    unsigned base = b0 * (3u * GPB) + g;                     // element offset, fits 32b

#pragma unroll
    for (int it = 0; it < ITERS; ++it, base += IT_STEP) {
        const f32x4 x0 = __builtin_nontemporal_load(x + base);
        const f32x4 x1 = __builtin_nontemporal_load(x + base + GPB);
        const f32x4 x2 = __builtin_nontemporal_load(x + base + 2u * GPB);

        f32x4 o0, o1, o2;
        o0.x = fmaf(w00, x0.x, fmaf(w01, x1.x, w02 * x2.x));
        o0.y = fmaf(w00, x0.y, fmaf(w01, x1.y, w02 * x2.y));
        o0.z = fmaf(w00, x0.z, fmaf(w01, x1.z, w02 * x2.z));
        o0.w = fmaf(w00, x0.w, fmaf(w01, x1.w, w02 * x2.w));

        o1.x = fmaf(w10, x0.x, fmaf(w11, x1.x, w12 * x2.x));
        o1.y = fmaf(w10, x0.y, fmaf(w11, x1.y, w12 * x2.y));
        o1.z = fmaf(w10, x0.z, fmaf(w11, x1.z, w12 * x2.z));
        o1.w = fmaf(w10, x0.w, fmaf(w11, x1.w, w12 * x2.w));

        o2.x = fmaf(w20, x0.x, fmaf(w21, x1.x, w22 * x2.x));
        o2.y = fmaf(w20, x0.y, fmaf(w21, x1.y, w22 * x2.y));
        o2.z = fmaf(w20, x0.z, fmaf(w21, x1.z, w22 * x2.z));
        o2.w = fmaf(w20, x0.w, fmaf(w21, x1.w, w22 * x2.w));

        __builtin_nontemporal_store(o0, out + base);
        __builtin_nontemporal_store(o1, out + base + GPB);
        __builtin_nontemporal_store(o2, out + base + 2u * GPB);
    }
}

extern "C" void kernel_launch(void* const* d_in, const int* in_sizes, int n_in,
                              void* d_out, int out_size, void* d_ws, size_t ws_size,
                              hipStream_t stream)
{
    const f32x4* x = (const f32x4*)d_in[0];
    const float* w = (const float*)d_in[1];
    f32x4*       o = (f32x4*)d_out;

    rot_kernel<<<dim3(GRID), dim3(BLOCK), 0, stream>>>(x, w, o);
}

// Round 4
// 318.068 us; speedup vs baseline: 1.0285x; 1.0145x over previous
//
#include <hip/hip_runtime.h>

// out[b,i,n] = sum_j w[i,j] * x[b,j,n]
// x: [B=256, 3, N=65536] fp32, w: [3,3] fp32, out: [B, 3, N] fp32.
// Pure streaming map: 402 MB HBM traffic, FLOPs negligible -> HBM-bound.
//
// Round-4 structural change: contiguous-sweep block mapping.
//   blockIdx (0..2047) -> b = blockIdx>>3 (0..255), chunk = blockIdx&7.
//   Each block owns 2048 consecutive float4 groups of batch b:
//     g = chunk*2048 + it*256 + tid, it = 0..7.
//   So each block sweeps exactly 6 contiguous 32 KiB streams (3 read rows
//   j=0..2 at GPB stride, 3 write rows) with NO inter-iteration jumps --
//   the previous version advanced b by 32 per iteration, touching 6 fresh
//   24-MiB-apart streams every iteration (DRAM page thrash; measured as
//   the ~5.2 vs 6.3 TB/s copy-ceiling gap).
//   Kept fixed from last round: 2048x256 grid (8 wg/CU), full 8x unroll
//   (24 independent in-flight loads), 32-bit address math, nt hints.

typedef float f32x4 __attribute__((ext_vector_type(4)));

#define B_DIM    256
#define N_DIM    65536
#define GPB      (N_DIM / 4)          // float4 groups per (b, j) row = 16384
#define BLOCK    256
#define GRID     2048                 // 8 wg/CU * 256 CU
#define ITERS    8                    // 2048 groups per block / 256 threads

__global__ __launch_bounds__(BLOCK) void rot_kernel(
    const f32x4* __restrict__ x,
    const float* __restrict__ w,
    f32x4*       __restrict__ out)
{
    // 3x3 weight: wave-uniform addresses -> scalar loads, fully cached
    const float w00 = w[0], w01 = w[1], w02 = w[2];
    const float w10 = w[3], w11 = w[4], w12 = w[5];
    const float w20 = w[6], w21 = w[7], w22 = w[8];

    const unsigned bid   = blockIdx.x;          // 0..2047
    const unsigned b     = bid >> 3;            // 0..255
    const unsigned chunk = bid & 7u;            // 0..7

    // element offset (float4 units); max = 255*49152 + 7*2048 + 2047 < 2^24
    unsigned base = b * (3u * GPB) + chunk * 2048u + threadIdx.x;

#pragma unroll
    for (int it = 0; it < ITERS; ++it, base += BLOCK) {
        const f32x4 x0 = __builtin_nontemporal_load(x + base);
        const f32x4 x1 = __builtin_nontemporal_load(x + base + GPB);
        const f32x4 x2 = __builtin_nontemporal_load(x + base + 2u * GPB);

        f32x4 o0, o1, o2;
        o0.x = fmaf(w00, x0.x, fmaf(w01, x1.x, w02 * x2.x));
        o0.y = fmaf(w00, x0.y, fmaf(w01, x1.y, w02 * x2.y));
        o0.z = fmaf(w00, x0.z, fmaf(w01, x1.z, w02 * x2.z));
        o0.w = fmaf(w00, x0.w, fmaf(w01, x1.w, w02 * x2.w));

        o1.x = fmaf(w10, x0.x, fmaf(w11, x1.x, w12 * x2.x));
        o1.y = fmaf(w10, x0.y, fmaf(w11, x1.y, w12 * x2.y));
        o1.z = fmaf(w10, x0.z, fmaf(w11, x1.z, w12 * x2.z));
        o1.w = fmaf(w10, x0.w, fmaf(w11, x1.w, w12 * x2.w));

        o2.x = fmaf(w20, x0.x, fmaf(w21, x1.x, w22 * x2.x));
        o2.y = fmaf(w20, x0.y, fmaf(w21, x1.y, w22 * x2.y));
        o2.z = fmaf(w20, x0.z, fmaf(w21, x1.z, w22 * x2.z));
        o2.w = fmaf(w20, x0.w, fmaf(w21, x1.w, w22 * x2.w));

        __builtin_nontemporal_store(o0, out + base);
        __builtin_nontemporal_store(o1, out + base + GPB);
        __builtin_nontemporal_store(o2, out + base + 2u * GPB);
    }
}

extern "C" void kernel_launch(void* const* d_in, const int* in_sizes, int n_in,
                              void* d_out, int out_size, void* d_ws, size_t ws_size,
                              hipStream_t stream)
{
    const f32x4* x = (const f32x4*)d_in[0];
    const float* w = (const float*)d_in[1];
    f32x4*       o = (f32x4*)d_out;

    rot_kernel<<<dim3(GRID), dim3(BLOCK), 0, stream>>>(x, w, o);
}